// Round 2
// baseline (1663.959 us; speedup 1.0000x reference)
//
#include <hip/hip_runtime.h>
#include <hip/hip_bf16.h>
#include <cstdint>

#define NTOPK 64
#define A_TOT 340
#define MS 28

// d_out element offsets (f32)
#define OFF_SCORES 0
#define OFF_BOXES  128
#define OFF_LABELS 640
#define OFF_MASKS  768
#define OFF_KEEP   33555200ull

__device__ __forceinline__ float sigmoidf_(float x) { return 1.f / (1.f + expf(-x)); }

// ---------------- Kernel A: decode + stable top-64 + NMS + small outputs ----
__global__ __launch_bounds__(384) void k_decode(
    const float* __restrict__ p0, const float* __restrict__ p1,
    const float* __restrict__ p2, const float* __restrict__ p3,
    float* __restrict__ out,
    float* __restrict__ ws_boxes, int* __restrict__ ws_keep,
    int* __restrict__ ws_boxint)
{
  const int b = blockIdx.x;
  const int t = threadIdx.x;
  __shared__ float sc[A_TOT];
  __shared__ float bx[A_TOT][4];
  __shared__ float tk_score[NTOPK];
  __shared__ float tk_box[NTOPK][4];
  __shared__ float tk_area[NTOPK];
  __shared__ int   keep_s[NTOPK];

  if (t < A_TOT) {
    const float* pp; int W, HW, la; float stride;
    if (t < 256)      { pp = p0; W = 16; HW = 256; la = t;       stride = 32.f;  }
    else if (t < 320) { pp = p1; W = 8;  HW = 64;  la = t - 256; stride = 64.f;  }
    else if (t < 336) { pp = p2; W = 4;  HW = 16;  la = t - 320; stride = 128.f; }
    else              { pp = p3; W = 2;  HW = 4;   la = t - 336; stride = 256.f; }
    const float* base = pp + (size_t)b * 6 * HW + la;
    float v0 = base[0], v1 = base[HW], v2 = base[2 * HW], v3 = base[3 * HW], v4 = base[4 * HW];
    int gx = la % W, gy = la / W;
    float cx = (v0 + (float)gx) * stride;
    float cy = (v1 + (float)gy) * stride;
    float w_ = expf(v2) * stride;
    float h_ = expf(v3) * stride;
    float score = sigmoidf_(v4);
    sc[t] = (score > 0.5f) ? score : 0.f;   // where(valid, score, 0)
    bx[t][0] = cx - 0.5f * w_;
    bx[t][1] = cy - 0.5f * h_;
    bx[t][2] = cx + 0.5f * w_;
    bx[t][3] = cy + 0.5f * h_;
  }
  __syncthreads();

  // stable top-k by rank counting (ties -> lower index first, like lax.top_k)
  if (t < A_TOT) {
    float my = sc[t];
    int rank = 0;
    for (int j = 0; j < A_TOT; ++j) {
      float o = sc[j];
      rank += (o > my) || (o == my && j < t);
    }
    if (rank < NTOPK) {
      tk_score[rank] = my;
      tk_box[rank][0] = bx[t][0];
      tk_box[rank][1] = bx[t][1];
      tk_box[rank][2] = bx[t][2];
      tk_box[rank][3] = bx[t][3];
    }
  }
  __syncthreads();

  if (t < NTOPK) {
    float x0 = tk_box[t][0], y0 = tk_box[t][1], x1 = tk_box[t][2], y1 = tk_box[t][3];
    tk_area[t] = fmaxf(x1 - x0, 0.f) * fmaxf(y1 - y0, 0.f);
    keep_s[t] = (tk_score[t] > 0.5f) ? 1 : 0;
  }
  __syncthreads();

  // sequential NMS (labels are always 0 -> no class offset needed)
  for (int i = 0; i < NTOPK - 1; ++i) {
    if (t < NTOPK && t > i && keep_s[i] && keep_s[t]) {
      float ix0 = fmaxf(tk_box[i][0], tk_box[t][0]);
      float iy0 = fmaxf(tk_box[i][1], tk_box[t][1]);
      float ix1 = fminf(tk_box[i][2], tk_box[t][2]);
      float iy1 = fminf(tk_box[i][3], tk_box[t][3]);
      float inter = fmaxf(ix1 - ix0, 0.f) * fmaxf(iy1 - iy0, 0.f);
      float uni = tk_area[i] + tk_area[t] - inter;
      float iou = inter / fmaxf(uni, 1e-9f);
      if (iou > 0.5f) keep_s[t] = 0;
    }
    __syncthreads();
  }

  if (t < NTOPK) {
    int box = b * NTOPK + t;
    float s = tk_score[t];
    int kp = keep_s[t];
    out[OFF_SCORES + box] = kp ? s : 0.f;
    #pragma unroll
    for (int c = 0; c < 4; ++c) {
      float bv = tk_box[t][c];
      out[OFF_BOXES + box * 4 + c] = bv;
      ws_boxes[box * 4 + c] = bv;
      float bc = fminf(fmaxf(bv, 0.f), 511.f);
      ws_boxint[box * 4 + c] = (int)bc;   // trunc == floor for >=0
    }
    out[OFF_LABELS + box] = 0.f;
    out[OFF_KEEP + box] = kp ? 1.f : 0.f;
    ws_keep[box] = kp;
  }
}

// ---------------- Kernel B: zero logits workspace ---------------------------
__global__ void k_zero(float* __restrict__ lg) {
  lg[blockIdx.x * 256 + threadIdx.x] = 0.f;
}

// -------- Kernel C: ROI-align (on the fly) + conv1 3x3 + SiLU + conv2 ------
// grid: 128 boxes x 4 co-groups x 4 row-quarters = 2048 blocks, 256 threads
#define CCH 16   // input-channel chunk
__global__ __launch_bounds__(256) void k_roiconv(
    const float* __restrict__ f0, const float* __restrict__ f1,
    const float* __restrict__ f2, const float* __restrict__ f3,
    const float* __restrict__ w1, const float* __restrict__ b1,
    const float* __restrict__ w2,
    const float* __restrict__ ws_boxes, const int* __restrict__ ws_keep,
    float* __restrict__ ws_logit)
{
  const int bid = blockIdx.x;
  const int box = bid >> 4;
  const int cog = (bid >> 2) & 3;   // output-channel group of 32
  const int rq  = bid & 3;          // row quarter (7 rows)
  if (!ws_keep[box]) return;
  const int b = box >> 6;
  const int t = threadIdx.x;
  const int r0 = rq * 7;

  __shared__ float boxv[4];
  __shared__ int   xi0[MS], xi1[MS], yi0[MS], yi1[MS];
  __shared__ float fxv[MS], fyv[MS];
  __shared__ float roi_lds[CCH][9][32];   // [ci][conv-in row][col+1], cols 0..29 used
  __shared__ float w_lds[CCH][9][36];     // [ci][tap][co_local(32, padded)]

  if (t < 4) boxv[t] = ws_boxes[box * 4 + t];
  __syncthreads();
  if (t < MS) {
    float b0 = boxv[0] * 0.25f, b1_ = boxv[1] * 0.25f;
    float b2_ = boxv[2] * 0.25f, b3_ = boxv[3] * 0.25f;
    float bw = (b2_ - b0) * (1.f / MS);
    float bh = (b3_ - b1_) * (1.f / MS);
    float x = b0 + ((float)t + 0.5f) * bw;
    x = fminf(fmaxf(x, 0.f), 127.f);
    int x0 = (int)floorf(x);
    xi0[t] = x0; xi1[t] = min(x0 + 1, 127); fxv[t] = x - (float)x0;
    float y = b1_ + ((float)t + 0.5f) * bh;
    y = fminf(fmaxf(y, 0.f), 127.f);
    int y0 = (int)floorf(y);
    yi0[t] = y0; yi1[t] = min(y0 + 1, 127); fyv[t] = y - (float)y0;
  }
  __syncthreads();

  const int cot = t & 7;    // 4 output channels each: co_l = cot*4 + j
  const int pg  = t >> 3;   // pixel group 0..31, px p = pg + 32*i
  int pr_[7], pc_[7];
  #pragma unroll
  for (int i = 0; i < 7; ++i) {
    int p = pg + 32 * i;
    if (p >= 196) p = 0;
    pr_[i] = p / 28;
    pc_[i] = p % 28;
  }

  float acc[4][7];
  #pragma unroll
  for (int j = 0; j < 4; ++j)
    #pragma unroll
    for (int i = 0; i < 7; ++i) acc[j][i] = 0.f;

  for (int cc = 0; cc < 256 / CCH; ++cc) {
    // stage weights: 32 co x 16 ci x 9 taps
    for (int e = t; e < 32 * CCH * 9; e += 256) {
      int co_l = e / (CCH * 9);
      int r = e % (CCH * 9);
      int ci_l = r / 9, tap = r % 9;
      w_lds[ci_l][tap][co_l] =
          w1[(size_t)(cog * 32 + co_l) * 2304 + (size_t)(cc * CCH + ci_l) * 9 + tap];
    }
    // stage ROI tile: 16 ci x 9 conv-in rows x 30 cols (with zero pad)
    for (int e = t; e < CCH * 9 * 30; e += 256) {
      int ci_l = e / 270;
      int r = e % 270;
      int rr = r / 30, c = r % 30;
      int gr = r0 - 1 + rr;   // conv input row in [-1,28]
      int gc = c - 1;         // conv input col in [-1,28]
      float v = 0.f;
      if (gr >= 0 && gr < MS && gc >= 0 && gc < MS) {
        int ci = cc * CCH + ci_l;
        const float* fp; int sh, Wp;
        if (ci < 64)       { fp = f0 + ((size_t)b * 64 + ci) * 16384;        sh = 0; Wp = 128; }
        else if (ci < 128) { fp = f1 + ((size_t)b * 64 + (ci - 64)) * 4096;  sh = 1; Wp = 64;  }
        else if (ci < 192) { fp = f2 + ((size_t)b * 64 + (ci - 128)) * 1024; sh = 2; Wp = 32;  }
        else               { fp = f3 + ((size_t)b * 64 + (ci - 192)) * 256;  sh = 3; Wp = 16;  }
        int ya = yi0[gr] >> sh, yb = yi1[gr] >> sh;
        int xa = xi0[gc] >> sh, xb = xi1[gc] >> sh;
        float fy = fyv[gr], fx = fxv[gc];
        float v00 = fp[ya * Wp + xa];
        float v01 = fp[ya * Wp + xb];
        float v10 = fp[yb * Wp + xa];
        float v11 = fp[yb * Wp + xb];
        v = v00 * (1.f - fy) * (1.f - fx) + v01 * (1.f - fy) * fx +
            v10 * fy * (1.f - fx) + v11 * fy * fx;
      }
      roi_lds[ci_l][rr][c] = v;
    }
    __syncthreads();

    for (int ci_l = 0; ci_l < CCH; ++ci_l) {
      #pragma unroll
      for (int tap = 0; tap < 9; ++tap) {
        const int dy = tap / 3, dx = tap % 3;
        float4 wv = *(const float4*)&w_lds[ci_l][tap][cot * 4];
        #pragma unroll
        for (int i = 0; i < 7; ++i) {
          float rv = roi_lds[ci_l][pr_[i] + dy][pc_[i] + dx];
          acc[0][i] = fmaf(wv.x, rv, acc[0][i]);
          acc[1][i] = fmaf(wv.y, rv, acc[1][i]);
          acc[2][i] = fmaf(wv.z, rv, acc[2][i]);
          acc[3][i] = fmaf(wv.w, rv, acc[3][i]);
        }
      }
    }
    __syncthreads();
  }

  // epilogue: +b1, SiLU, dot with w2, reduce over the 8 co-threads, atomicAdd
  float bias[4], wo[4];
  #pragma unroll
  for (int j = 0; j < 4; ++j) {
    int co = cog * 32 + cot * 4 + j;
    bias[j] = b1[co];
    wo[j] = w2[co];
  }
  float part[7];
  #pragma unroll
  for (int i = 0; i < 7; ++i) {
    float sum = 0.f;
    #pragma unroll
    for (int j = 0; j < 4; ++j) {
      float h = acc[j][i] + bias[j];
      float s = h * sigmoidf_(h);   // silu
      sum = fmaf(wo[j], s, sum);
    }
    part[i] = sum;
  }
  #pragma unroll
  for (int d = 1; d < 8; d <<= 1) {
    #pragma unroll
    for (int i = 0; i < 7; ++i) part[i] += __shfl_xor(part[i], d);
  }
  if (cot == 0) {
    #pragma unroll
    for (int i = 0; i < 7; ++i) {
      int p = pg + 32 * i;
      if (p < 196) atomicAdd(&ws_logit[(size_t)box * 784 + r0 * 28 + p], part[i]);
    }
  }
}

// ---------------- Kernel D: sigmoid + paste + binarize (f32 out) ------------
__global__ __launch_bounds__(256) void k_paste(
    const float* __restrict__ ws_logit, const int* __restrict__ ws_keep,
    const int* __restrict__ ws_boxint, const float* __restrict__ b2,
    float* __restrict__ out)
{
  const int box = blockIdx.x;
  const int t = threadIdx.x;
  float* mb = out + OFF_MASKS + (size_t)box * 262144;

  if (!ws_keep[box]) {
    uint4 z = {0u, 0u, 0u, 0u};
    uint4* p = (uint4*)mb;
    for (int e = t; e < 65536; e += 256) p[e] = z;
    return;
  }

  __shared__ float soft[784];
  __shared__ int ixs[512], iys[512];
  __shared__ int bi[4];
  if (t < 4) bi[t] = ws_boxint[box * 4 + t];
  __syncthreads();
  const int x0 = bi[0], y0 = bi[1], x1 = bi[2], y1 = bi[3];
  const int w = x1 - x0 + 1, h = y1 - y0 + 1;
  const float b2v = b2[0];

  for (int e = t; e < 784; e += 256)
    soft[e] = sigmoidf_(ws_logit[(size_t)box * 784 + e] + b2v);
  for (int e = t; e < 512; e += 256) {
    int vx = (e - x0) * MS;
    int ix = (vx >= 0) ? (vx / w) : 0;   // negatives clip to 0 anyway
    ixs[e] = min(max(ix, 0), MS - 1);
    int vy = (e - y0) * MS;
    int iy = (vy >= 0) ? (vy / h) : 0;
    iys[e] = min(max(iy, 0), MS - 1);
  }
  __syncthreads();

  const unsigned FONE = 0x3F800000u;  // f32 1.0
  for (int it = 0; it < 128; ++it) {
    int Y = it * 4 + (t >> 6);
    int Xb = (t & 63) * 8;
    bool rowin = (Y >= y0) && (Y <= y1);
    int iy = iys[Y];
    unsigned v[8];
    #pragma unroll
    for (int u = 0; u < 8; ++u) {
      int X = Xb + u;
      bool in = rowin && (X >= x0) && (X <= x1);
      float g = soft[iy * MS + ixs[X]];
      v[u] = (in && g > 0.5f) ? FONE : 0u;
    }
    uint4 pk0, pk1;
    pk0.x = v[0]; pk0.y = v[1]; pk0.z = v[2]; pk0.w = v[3];
    pk1.x = v[4]; pk1.y = v[5]; pk1.z = v[6]; pk1.w = v[7];
    *(uint4*)(mb + (size_t)Y * 512 + Xb) = pk0;
    *(uint4*)(mb + (size_t)Y * 512 + Xb + 4) = pk1;
  }
}

extern "C" void kernel_launch(void* const* d_in, const int* in_sizes, int n_in,
                              void* d_out, int out_size, void* d_ws, size_t ws_size,
                              hipStream_t stream) {
  const float* p0 = (const float*)d_in[0];
  const float* p1 = (const float*)d_in[1];
  const float* p2 = (const float*)d_in[2];
  const float* p3 = (const float*)d_in[3];
  const float* f0 = (const float*)d_in[4];
  const float* f1 = (const float*)d_in[5];
  const float* f2 = (const float*)d_in[6];
  const float* f3 = (const float*)d_in[7];
  const float* w1 = (const float*)d_in[8];
  const float* b1 = (const float*)d_in[9];
  const float* w2 = (const float*)d_in[10];
  const float* b2 = (const float*)d_in[11];
  float* out = (float*)d_out;

  float* wsf = (float*)d_ws;
  float* ws_boxes  = wsf;                 // 512 f32
  int*   ws_keep   = (int*)(wsf + 512);   // 128 i32
  int*   ws_boxint = (int*)(wsf + 640);   // 512 i32
  float* ws_logit  = wsf + 1152;          // 128*784 f32

  k_decode<<<2, 384, 0, stream>>>(p0, p1, p2, p3, out, ws_boxes, ws_keep, ws_boxint);
  k_zero<<<392, 256, 0, stream>>>(ws_logit);   // 392*256 == 128*784
  k_roiconv<<<2048, 256, 0, stream>>>(f0, f1, f2, f3, w1, b1, w2,
                                      ws_boxes, ws_keep, ws_logit);
  k_paste<<<128, 256, 0, stream>>>(ws_logit, ws_keep, ws_boxint, b2, out);
}

// Round 3
// 440.448 us; speedup vs baseline: 3.7779x; 3.7779x over previous
//
#include <hip/hip_runtime.h>
#include <hip/hip_bf16.h>
#include <cstdint>

#define NTOPK 64
#define A_TOT 340
#define MS 28

// d_out element offsets (f32)
#define OFF_SCORES 0
#define OFF_BOXES  128
#define OFF_LABELS 640
#define OFF_MASKS  768
#define OFF_KEEP   33555200ull

typedef __attribute__((ext_vector_type(8))) short bf16x8;
typedef __attribute__((ext_vector_type(4))) float f32x4;

__device__ __forceinline__ float sigmoidf_(float x) { return 1.f / (1.f + expf(-x)); }
__device__ __forceinline__ float bf2f(unsigned short u) {
  return __uint_as_float(((unsigned)u) << 16);
}
__device__ __forceinline__ unsigned short f2bf(float f) {
  __hip_bfloat16 h = __float2bfloat16(f);  // RNE
  return *(unsigned short*)&h;
}

// ---------------- Kernel A: decode + stable top-64 + NMS + small outputs ----
__global__ __launch_bounds__(384) void k_decode(
    const float* __restrict__ p0, const float* __restrict__ p1,
    const float* __restrict__ p2, const float* __restrict__ p3,
    float* __restrict__ out,
    float* __restrict__ ws_boxes, int* __restrict__ ws_keep,
    int* __restrict__ ws_boxint)
{
  const int b = blockIdx.x;
  const int t = threadIdx.x;
  __shared__ float sc[A_TOT];
  __shared__ float bx[A_TOT][4];
  __shared__ float tk_score[NTOPK];
  __shared__ float tk_box[NTOPK][4];
  __shared__ float tk_area[NTOPK];
  __shared__ int   keep_s[NTOPK];

  if (t < A_TOT) {
    const float* pp; int W, HW, la; float stride;
    if (t < 256)      { pp = p0; W = 16; HW = 256; la = t;       stride = 32.f;  }
    else if (t < 320) { pp = p1; W = 8;  HW = 64;  la = t - 256; stride = 64.f;  }
    else if (t < 336) { pp = p2; W = 4;  HW = 16;  la = t - 320; stride = 128.f; }
    else              { pp = p3; W = 2;  HW = 4;   la = t - 336; stride = 256.f; }
    const float* base = pp + (size_t)b * 6 * HW + la;
    float v0 = base[0], v1 = base[HW], v2 = base[2 * HW], v3 = base[3 * HW], v4 = base[4 * HW];
    int gx = la % W, gy = la / W;
    float cx = (v0 + (float)gx) * stride;
    float cy = (v1 + (float)gy) * stride;
    float w_ = expf(v2) * stride;
    float h_ = expf(v3) * stride;
    float score = sigmoidf_(v4);
    sc[t] = (score > 0.5f) ? score : 0.f;
    bx[t][0] = cx - 0.5f * w_;
    bx[t][1] = cy - 0.5f * h_;
    bx[t][2] = cx + 0.5f * w_;
    bx[t][3] = cy + 0.5f * h_;
  }
  __syncthreads();

  if (t < A_TOT) {
    float my = sc[t];
    int rank = 0;
    for (int j = 0; j < A_TOT; ++j) {
      float o = sc[j];
      rank += (o > my) || (o == my && j < t);
    }
    if (rank < NTOPK) {
      tk_score[rank] = my;
      tk_box[rank][0] = bx[t][0];
      tk_box[rank][1] = bx[t][1];
      tk_box[rank][2] = bx[t][2];
      tk_box[rank][3] = bx[t][3];
    }
  }
  __syncthreads();

  if (t < NTOPK) {
    float x0 = tk_box[t][0], y0 = tk_box[t][1], x1 = tk_box[t][2], y1 = tk_box[t][3];
    tk_area[t] = fmaxf(x1 - x0, 0.f) * fmaxf(y1 - y0, 0.f);
    keep_s[t] = (tk_score[t] > 0.5f) ? 1 : 0;
  }
  __syncthreads();

  for (int i = 0; i < NTOPK - 1; ++i) {
    if (t < NTOPK && t > i && keep_s[i] && keep_s[t]) {
      float ix0 = fmaxf(tk_box[i][0], tk_box[t][0]);
      float iy0 = fmaxf(tk_box[i][1], tk_box[t][1]);
      float ix1 = fminf(tk_box[i][2], tk_box[t][2]);
      float iy1 = fminf(tk_box[i][3], tk_box[t][3]);
      float inter = fmaxf(ix1 - ix0, 0.f) * fmaxf(iy1 - iy0, 0.f);
      float uni = tk_area[i] + tk_area[t] - inter;
      float iou = inter / fmaxf(uni, 1e-9f);
      if (iou > 0.5f) keep_s[t] = 0;
    }
    __syncthreads();
  }

  if (t < NTOPK) {
    int box = b * NTOPK + t;
    float s = tk_score[t];
    int kp = keep_s[t];
    out[OFF_SCORES + box] = kp ? s : 0.f;
    #pragma unroll
    for (int c = 0; c < 4; ++c) {
      float bv = tk_box[t][c];
      out[OFF_BOXES + box * 4 + c] = bv;
      ws_boxes[box * 4 + c] = bv;
      float bc = fminf(fmaxf(bv, 0.f), 511.f);
      ws_boxint[box * 4 + c] = (int)bc;
    }
    out[OFF_LABELS + box] = 0.f;
    out[OFF_KEEP + box] = kp ? 1.f : 0.f;
    ws_keep[box] = kp;
  }
}

// ------- Kernel T: build merged[b][y][x][c] bf16 (nearest-resize folded) ----
__global__ __launch_bounds__(256) void k_transpose(
    const float* __restrict__ f0, const float* __restrict__ f1,
    const float* __restrict__ f2, const float* __restrict__ f3,
    unsigned short* __restrict__ mg)
{
  const int b = blockIdx.x >> 7;
  const int y = blockIdx.x & 127;
  const int t = threadIdx.x;
  // stride 260 shorts = 520B: 8B-aligned short4 reads, 2-way (free) bank aliasing
  __shared__ unsigned short tile[128 * 260];
  const int x = t & 127, ch = t >> 7;

  {
    const float* src = f0 + ((size_t)b * 64) * 16384 + y * 128 + x;
    for (int cc = 0; cc < 32; ++cc) {
      int cl = ch * 32 + cc;
      tile[x * 260 + cl] = f2bf(src[(size_t)cl * 16384]);
    }
  }
  {
    const float* src = f1 + ((size_t)b * 64) * 4096 + (y >> 1) * 64 + (x >> 1);
    for (int cc = 0; cc < 32; ++cc) {
      int cl = ch * 32 + cc;
      tile[x * 260 + 64 + cl] = f2bf(src[(size_t)cl * 4096]);
    }
  }
  {
    const float* src = f2 + ((size_t)b * 64) * 1024 + (y >> 2) * 32 + (x >> 2);
    for (int cc = 0; cc < 32; ++cc) {
      int cl = ch * 32 + cc;
      tile[x * 260 + 128 + cl] = f2bf(src[(size_t)cl * 1024]);
    }
  }
  {
    const float* src = f3 + ((size_t)b * 64) * 256 + (y >> 3) * 16 + (x >> 3);
    for (int cc = 0; cc < 32; ++cc) {
      int cl = ch * 32 + cc;
      tile[x * 260 + 192 + cl] = f2bf(src[(size_t)cl * 256]);
    }
  }
  __syncthreads();
  unsigned short* dst = mg + (((size_t)b * 128 + y) * 128) * 256;
  for (int it = 0; it < 32; ++it) {
    int qq = t + it * 256;
    int xx = qq >> 6, cg = qq & 63;
    *(ushort4*)(dst + xx * 256 + cg * 4) = *(ushort4*)&tile[xx * 260 + cg * 4];
  }
}

// ------- Kernel W: w1 f32 [co][ci][3][3] -> wt bf16 [tap][co][ci] ----------
__global__ __launch_bounds__(256) void k_transw(
    const float* __restrict__ w1, unsigned short* __restrict__ wt)
{
  const int co = blockIdx.x;
  const int ci = threadIdx.x;
  const float* src = w1 + ((size_t)co * 256 + ci) * 9;
  #pragma unroll
  for (int tap = 0; tap < 9; ++tap)
    wt[((size_t)tap * 128 + co) * 256 + ci] = f2bf(src[tap]);
}

// ------- Kernel C: fused ROI-align + conv1(3x3) MFMA + SiLU + conv2 --------
// grid: 128 boxes x 4 row-quarters; 256 threads (4 waves)
// wave wv: nthalf = wv&1 (pixel tiles 0..6 / 7..13), cohalf = wv>>1 (co 0..63 / 64..127)
__global__ __launch_bounds__(256) void k_roiconv2(
    const unsigned short* __restrict__ mg,   // [2][128][128][256] bf16
    const unsigned short* __restrict__ wt,   // [9][128][256] bf16
    const float* __restrict__ b1, const float* __restrict__ w2,
    const float* __restrict__ ws_boxes, const int* __restrict__ ws_keep,
    float* __restrict__ ws_logit)
{
  const int box = blockIdx.x >> 2;
  const int q   = blockIdx.x & 3;
  if (!ws_keep[box]) return;
  const int b = box >> 6;
  const int t = threadIdx.x;

  __shared__ float boxv[4];
  __shared__ int xi0[MS], xi1[MS], yi0[MS], yi1[MS];
  __shared__ float fxv[MS], fyv[MS];
  // [buf 2][row 9][col 32][ci 32] bf16 : 64B per pixel cell -> conflict-free b128
  __shared__ unsigned short roi[2 * 9 * 32 * 32];
  __shared__ float lsum[2][7][16][2];

  if (t < 4) boxv[t] = ws_boxes[box * 4 + t];
  __syncthreads();
  if (t < MS) {
    float b0 = boxv[0] * 0.25f, b1_ = boxv[1] * 0.25f;
    float b2_ = boxv[2] * 0.25f, b3_ = boxv[3] * 0.25f;
    float bw = (b2_ - b0) * (1.f / MS);
    float bh = (b3_ - b1_) * (1.f / MS);
    float x = b0 + ((float)t + 0.5f) * bw;
    x = fminf(fmaxf(x, 0.f), 127.f);
    int x0 = (int)floorf(x);
    xi0[t] = x0; xi1[t] = min(x0 + 1, 127); fxv[t] = x - (float)x0;
    float y = b1_ + ((float)t + 0.5f) * bh;
    y = fminf(fmaxf(y, 0.f), 127.f);
    int y0 = (int)floorf(y);
    yi0[t] = y0; yi1[t] = min(y0 + 1, 127); fyv[t] = y - (float)y0;
  }
  {
    ushort4 z = {0, 0, 0, 0};
    for (int e = t; e < (2 * 9 * 32 * 32) / 4; e += 256) ((ushort4*)roi)[e] = z;
  }
  __syncthreads();

  const int lane = t & 63, wv = t >> 6;
  const int laneN = lane & 15, kg = lane >> 4;
  const int nthalf = wv & 1, cohalf = wv >> 1;
  const int cobase = cohalf * 64;
  const int y0m1 = q * 7 - 1;
  const unsigned short* mgb = mg + ((size_t)b * 128 * 128) * 256;

  // per-lane B cell base (shorts) for 7 n-tiles; tap adds an immediate offset
  int Bidx[7];
  #pragma unroll
  for (int i = 0; i < 7; ++i) {
    int p = nthalf * 112 + i * 16 + laneN;
    if (p > 195) p = 195;                 // pad lanes/tiles clamp (stores masked)
    int py = p / 28, px = p - py * 28;
    Bidx[i] = (py * 32 + px) * 32 + kg * 8;
  }

  f32x4 acc[4][7];
  #pragma unroll
  for (int mt = 0; mt < 4; ++mt)
    #pragma unroll
    for (int i = 0; i < 7; ++i) acc[mt][i] = (f32x4){0.f, 0.f, 0.f, 0.f};

  // ---- staging (fused bilinear sampling from merged, bf16 out) ----
  auto stage = [&](int cn) {
    unsigned short* dstbuf = roi + (cn & 1) * 9216;
    const int cb = cn * 32;
    for (int e = t; e < 2016; e += 256) {          // 9 rows x 28 cols x 8 ci-quads
      int cig = e & 7;
      int pix = e >> 3;
      int rr = pix / 28, gc = pix - rr * 28;
      int gr = y0m1 + rr;
      if ((unsigned)gr < 28u) {
        int ya = yi0[gr], yb = yi1[gr]; float fy = fyv[gr];
        int xa = xi0[gc], xb = xi1[gc]; float fx = fxv[gc];
        int cbase = cb + cig * 4;
        ushort4 u00 = *(const ushort4*)(mgb + ((size_t)(ya * 128 + xa)) * 256 + cbase);
        ushort4 u01 = *(const ushort4*)(mgb + ((size_t)(ya * 128 + xb)) * 256 + cbase);
        ushort4 u10 = *(const ushort4*)(mgb + ((size_t)(yb * 128 + xa)) * 256 + cbase);
        ushort4 u11 = *(const ushort4*)(mgb + ((size_t)(yb * 128 + xb)) * 256 + cbase);
        float w00 = (1.f - fy) * (1.f - fx), w01 = (1.f - fy) * fx;
        float w10 = fy * (1.f - fx),         w11 = fy * fx;
        ushort4 o;
        o.x = f2bf(bf2f(u00.x) * w00 + bf2f(u01.x) * w01 + bf2f(u10.x) * w10 + bf2f(u11.x) * w11);
        o.y = f2bf(bf2f(u00.y) * w00 + bf2f(u01.y) * w01 + bf2f(u10.y) * w10 + bf2f(u11.y) * w11);
        o.z = f2bf(bf2f(u00.z) * w00 + bf2f(u01.z) * w01 + bf2f(u10.z) * w10 + bf2f(u11.z) * w11);
        o.w = f2bf(bf2f(u00.w) * w00 + bf2f(u01.w) * w01 + bf2f(u10.w) * w10 + bf2f(u11.w) * w11);
        *(ushort4*)(dstbuf + (rr * 32 + gc + 1) * 32 + cig * 4) = o;
      }
    }
  };

  stage(0);
  __syncthreads();

  const bf16x8* wtl = (const bf16x8*)wt;
  for (int c = 0; c < 8; ++c) {
    if (c < 7) stage(c + 1);
    const unsigned short* rb = roi + (c & 1) * 9216;
    const int abase = (cobase + laneN) * 32 + c * 4 + kg;
    #pragma unroll
    for (int tap = 0; tap < 9; ++tap) {
      const int toff = ((tap / 3) * 32 + (tap % 3)) * 32;
      bf16x8 av[4];
      #pragma unroll
      for (int mt = 0; mt < 4; ++mt) av[mt] = wtl[abase + tap * 4096 + mt * 512];
      #pragma unroll
      for (int i = 0; i < 7; ++i) {
        bf16x8 bv = *(const bf16x8*)(rb + Bidx[i] + toff);
        #pragma unroll
        for (int mt = 0; mt < 4; ++mt)
          acc[mt][i] = __builtin_amdgcn_mfma_f32_16x16x32_bf16(av[mt], bv, acc[mt][i], 0, 0, 0);
      }
    }
    __syncthreads();
  }

  // ---- epilogue: +b1, SiLU, dot w2, reduce kg groups + co halves ----
  float b1v[4][4], w2v[4][4];
  #pragma unroll
  for (int mt = 0; mt < 4; ++mt)
    #pragma unroll
    for (int r = 0; r < 4; ++r) {
      int co = cobase + mt * 16 + kg * 4 + r;
      b1v[mt][r] = b1[co];
      w2v[mt][r] = w2[co];
    }
  #pragma unroll
  for (int i = 0; i < 7; ++i) {
    float part = 0.f;
    #pragma unroll
    for (int mt = 0; mt < 4; ++mt)
      #pragma unroll
      for (int r = 0; r < 4; ++r) {
        float h = acc[mt][i][r] + b1v[mt][r];
        part = fmaf(w2v[mt][r], h * sigmoidf_(h), part);
      }
    part += __shfl_xor(part, 16);
    part += __shfl_xor(part, 32);
    if (lane < 16) lsum[nthalf][i][laneN][cohalf] = part;
  }
  __syncthreads();
  if (t < 196) {
    int nh = t / 112, rem = t - nh * 112;
    int i = rem >> 4, n = rem & 15;
    ws_logit[(size_t)box * 784 + q * 196 + t] = lsum[nh][i][n][0] + lsum[nh][i][n][1];
  }
}

// ---------------- Kernel D: sigmoid + paste + binarize (f32 out) ------------
__global__ __launch_bounds__(256) void k_paste(
    const float* __restrict__ ws_logit, const int* __restrict__ ws_keep,
    const int* __restrict__ ws_boxint, const float* __restrict__ b2,
    float* __restrict__ out)
{
  const int box = blockIdx.x;
  const int t = threadIdx.x;
  float* mb = out + OFF_MASKS + (size_t)box * 262144;

  if (!ws_keep[box]) {
    uint4 z = {0u, 0u, 0u, 0u};
    uint4* p = (uint4*)mb;
    for (int e = t; e < 65536; e += 256) p[e] = z;
    return;
  }

  __shared__ float soft[784];
  __shared__ int ixs[512], iys[512];
  __shared__ int bi[4];
  if (t < 4) bi[t] = ws_boxint[box * 4 + t];
  __syncthreads();
  const int x0 = bi[0], y0 = bi[1], x1 = bi[2], y1 = bi[3];
  const int w = x1 - x0 + 1, h = y1 - y0 + 1;
  const float b2v = b2[0];

  for (int e = t; e < 784; e += 256)
    soft[e] = sigmoidf_(ws_logit[(size_t)box * 784 + e] + b2v);
  for (int e = t; e < 512; e += 256) {
    int vx = (e - x0) * MS;
    int ix = (vx >= 0) ? (vx / w) : 0;
    ixs[e] = min(max(ix, 0), MS - 1);
    int vy = (e - y0) * MS;
    int iy = (vy >= 0) ? (vy / h) : 0;
    iys[e] = min(max(iy, 0), MS - 1);
  }
  __syncthreads();

  const unsigned FONE = 0x3F800000u;
  for (int it = 0; it < 128; ++it) {
    int Y = it * 4 + (t >> 6);
    int Xb = (t & 63) * 8;
    bool rowin = (Y >= y0) && (Y <= y1);
    int iy = iys[Y];
    unsigned v[8];
    #pragma unroll
    for (int u = 0; u < 8; ++u) {
      int X = Xb + u;
      bool in = rowin && (X >= x0) && (X <= x1);
      float g = soft[iy * MS + ixs[X]];
      v[u] = (in && g > 0.5f) ? FONE : 0u;
    }
    uint4 pk0, pk1;
    pk0.x = v[0]; pk0.y = v[1]; pk0.z = v[2]; pk0.w = v[3];
    pk1.x = v[4]; pk1.y = v[5]; pk1.z = v[6]; pk1.w = v[7];
    *(uint4*)(mb + (size_t)Y * 512 + Xb) = pk0;
    *(uint4*)(mb + (size_t)Y * 512 + Xb + 4) = pk1;
  }
}

extern "C" void kernel_launch(void* const* d_in, const int* in_sizes, int n_in,
                              void* d_out, int out_size, void* d_ws, size_t ws_size,
                              hipStream_t stream) {
  const float* p0 = (const float*)d_in[0];
  const float* p1 = (const float*)d_in[1];
  const float* p2 = (const float*)d_in[2];
  const float* p3 = (const float*)d_in[3];
  const float* f0 = (const float*)d_in[4];
  const float* f1 = (const float*)d_in[5];
  const float* f2 = (const float*)d_in[6];
  const float* f3 = (const float*)d_in[7];
  const float* w1 = (const float*)d_in[8];
  const float* b1 = (const float*)d_in[9];
  const float* w2 = (const float*)d_in[10];
  const float* b2 = (const float*)d_in[11];
  float* out = (float*)d_out;

  float* wsf = (float*)d_ws;
  float*          ws_boxes  = wsf;                              // 512 f32
  int*            ws_keep   = (int*)(wsf + 512);                // 128 i32
  int*            ws_boxint = (int*)(wsf + 640);                // 512 i32
  float*          ws_logit  = wsf + 1152;                       // 128*784 f32
  unsigned short* ws_wt     = (unsigned short*)(wsf + 101504);  // 9*128*256 bf16
  unsigned short* ws_merged = (unsigned short*)(wsf + 248960);  // 2*128*128*256 bf16
  // total ws use: 4,443,264 f32 = 17.8 MB

  k_decode<<<2, 384, 0, stream>>>(p0, p1, p2, p3, out, ws_boxes, ws_keep, ws_boxint);
  k_transw<<<128, 256, 0, stream>>>(w1, ws_wt);
  k_transpose<<<256, 256, 0, stream>>>(f0, f1, f2, f3, ws_merged);
  k_roiconv2<<<512, 256, 0, stream>>>(ws_merged, ws_wt, b1, w2,
                                      ws_boxes, ws_keep, ws_logit);
  k_paste<<<128, 256, 0, stream>>>(ws_logit, ws_keep, ws_boxint, b2, out);
}

// Round 4
// 380.862 us; speedup vs baseline: 4.3689x; 1.1564x over previous
//
#include <hip/hip_runtime.h>
#include <hip/hip_bf16.h>
#include <cstdint>

#define NTOPK 64
#define A_TOT 340
#define MS 28

// d_out element offsets (f32)
#define OFF_SCORES 0
#define OFF_BOXES  128
#define OFF_LABELS 640
#define OFF_MASKS  768
#define OFF_KEEP   33555200ull

typedef __attribute__((ext_vector_type(8))) short bf16x8;
typedef __attribute__((ext_vector_type(4))) float f32x4;

__device__ __forceinline__ float sigmoidf_(float x) { return 1.f / (1.f + expf(-x)); }
__device__ __forceinline__ float bf2f(unsigned u) {
  return __uint_as_float(u << 16);
}
__device__ __forceinline__ unsigned short f2bf(float f) {
  __hip_bfloat16 h = __float2bfloat16(f);  // RNE
  return *(unsigned short*)&h;
}

// ---------------- Kernel A: decode + stable top-64 + NMS + small outputs ----
__global__ __launch_bounds__(384) void k_decode(
    const float* __restrict__ p0, const float* __restrict__ p1,
    const float* __restrict__ p2, const float* __restrict__ p3,
    float* __restrict__ out,
    float* __restrict__ ws_boxes, int* __restrict__ ws_keep,
    int* __restrict__ ws_boxint)
{
  const int b = blockIdx.x;
  const int t = threadIdx.x;
  __shared__ float sc[A_TOT];
  __shared__ float bx[A_TOT][4];
  __shared__ float tk_score[NTOPK];
  __shared__ float tk_box[NTOPK][4];
  __shared__ float tk_area[NTOPK];
  __shared__ int   keep_s[NTOPK];

  if (t < A_TOT) {
    const float* pp; int W, HW, la; float stride;
    if (t < 256)      { pp = p0; W = 16; HW = 256; la = t;       stride = 32.f;  }
    else if (t < 320) { pp = p1; W = 8;  HW = 64;  la = t - 256; stride = 64.f;  }
    else if (t < 336) { pp = p2; W = 4;  HW = 16;  la = t - 320; stride = 128.f; }
    else              { pp = p3; W = 2;  HW = 4;   la = t - 336; stride = 256.f; }
    const float* base = pp + (size_t)b * 6 * HW + la;
    float v0 = base[0], v1 = base[HW], v2 = base[2 * HW], v3 = base[3 * HW], v4 = base[4 * HW];
    int gx = la % W, gy = la / W;
    float cx = (v0 + (float)gx) * stride;
    float cy = (v1 + (float)gy) * stride;
    float w_ = expf(v2) * stride;
    float h_ = expf(v3) * stride;
    float score = sigmoidf_(v4);
    sc[t] = (score > 0.5f) ? score : 0.f;
    bx[t][0] = cx - 0.5f * w_;
    bx[t][1] = cy - 0.5f * h_;
    bx[t][2] = cx + 0.5f * w_;
    bx[t][3] = cy + 0.5f * h_;
  }
  __syncthreads();

  if (t < A_TOT) {
    float my = sc[t];
    int rank = 0;
    for (int j = 0; j < A_TOT; ++j) {
      float o = sc[j];
      rank += (o > my) || (o == my && j < t);
    }
    if (rank < NTOPK) {
      tk_score[rank] = my;
      tk_box[rank][0] = bx[t][0];
      tk_box[rank][1] = bx[t][1];
      tk_box[rank][2] = bx[t][2];
      tk_box[rank][3] = bx[t][3];
    }
  }
  __syncthreads();

  if (t < NTOPK) {
    float x0 = tk_box[t][0], y0 = tk_box[t][1], x1 = tk_box[t][2], y1 = tk_box[t][3];
    tk_area[t] = fmaxf(x1 - x0, 0.f) * fmaxf(y1 - y0, 0.f);
    keep_s[t] = (tk_score[t] > 0.5f) ? 1 : 0;
  }
  __syncthreads();

  for (int i = 0; i < NTOPK - 1; ++i) {
    if (t < NTOPK && t > i && keep_s[i] && keep_s[t]) {
      float ix0 = fmaxf(tk_box[i][0], tk_box[t][0]);
      float iy0 = fmaxf(tk_box[i][1], tk_box[t][1]);
      float ix1 = fminf(tk_box[i][2], tk_box[t][2]);
      float iy1 = fminf(tk_box[i][3], tk_box[t][3]);
      float inter = fmaxf(ix1 - ix0, 0.f) * fmaxf(iy1 - iy0, 0.f);
      float uni = tk_area[i] + tk_area[t] - inter;
      float iou = inter / fmaxf(uni, 1e-9f);
      if (iou > 0.5f) keep_s[t] = 0;
    }
    __syncthreads();
  }

  if (t < NTOPK) {
    int box = b * NTOPK + t;
    float s = tk_score[t];
    int kp = keep_s[t];
    out[OFF_SCORES + box] = kp ? s : 0.f;
    #pragma unroll
    for (int c = 0; c < 4; ++c) {
      float bv = tk_box[t][c];
      out[OFF_BOXES + box * 4 + c] = bv;
      ws_boxes[box * 4 + c] = bv;
      float bc = fminf(fmaxf(bv, 0.f), 511.f);
      ws_boxint[box * 4 + c] = (int)bc;
    }
    out[OFF_LABELS + box] = 0.f;
    out[OFF_KEEP + box] = kp ? 1.f : 0.f;
    ws_keep[box] = kp;
  }
}

// ------- Kernel T: build merged[b][y][x][c] bf16 (nearest-resize folded) ----
__global__ __launch_bounds__(256) void k_transpose(
    const float* __restrict__ f0, const float* __restrict__ f1,
    const float* __restrict__ f2, const float* __restrict__ f3,
    unsigned short* __restrict__ mg)
{
  const int b = blockIdx.x >> 7;
  const int y = blockIdx.x & 127;
  const int t = threadIdx.x;
  __shared__ unsigned short tile[128 * 260];
  const int x = t & 127, ch = t >> 7;

  {
    const float* src = f0 + ((size_t)b * 64) * 16384 + y * 128 + x;
    for (int cc = 0; cc < 32; ++cc) {
      int cl = ch * 32 + cc;
      tile[x * 260 + cl] = f2bf(src[(size_t)cl * 16384]);
    }
  }
  {
    const float* src = f1 + ((size_t)b * 64) * 4096 + (y >> 1) * 64 + (x >> 1);
    for (int cc = 0; cc < 32; ++cc) {
      int cl = ch * 32 + cc;
      tile[x * 260 + 64 + cl] = f2bf(src[(size_t)cl * 4096]);
    }
  }
  {
    const float* src = f2 + ((size_t)b * 64) * 1024 + (y >> 2) * 32 + (x >> 2);
    for (int cc = 0; cc < 32; ++cc) {
      int cl = ch * 32 + cc;
      tile[x * 260 + 128 + cl] = f2bf(src[(size_t)cl * 1024]);
    }
  }
  {
    const float* src = f3 + ((size_t)b * 64) * 256 + (y >> 3) * 16 + (x >> 3);
    for (int cc = 0; cc < 32; ++cc) {
      int cl = ch * 32 + cc;
      tile[x * 260 + 192 + cl] = f2bf(src[(size_t)cl * 256]);
    }
  }
  __syncthreads();
  unsigned short* dst = mg + (((size_t)b * 128 + y) * 128) * 256;
  for (int it = 0; it < 32; ++it) {
    int qq = t + it * 256;
    int xx = qq >> 6, cg = qq & 63;
    *(ushort4*)(dst + xx * 256 + cg * 4) = *(ushort4*)&tile[xx * 260 + cg * 4];
  }
}

// ------- Kernel W: w1 f32 [co][ci][3][3] -> wt bf16 [tap][co][ci] ----------
__global__ __launch_bounds__(256) void k_transw(
    const float* __restrict__ w1, unsigned short* __restrict__ wt)
{
  const int co = blockIdx.x;
  const int ci = threadIdx.x;
  const float* src = w1 + ((size_t)co * 256 + ci) * 9;
  #pragma unroll
  for (int tap = 0; tap < 9; ++tap)
    wt[((size_t)tap * 128 + co) * 256 + ci] = f2bf(src[tap]);
}

// ------- Kernel S: materialize ROI tiles, bilinear from merged --------------
// roi[box][r 0..29][cell 0..31][ci 256] bf16; r = input row+1, cell = col+1;
// pad rows/cells zeroed. ci quads (8ci=16B) stored swizzled: slot = qi^((cell>>1)&3)
__global__ __launch_bounds__(256) void k_roistage(
    const unsigned short* __restrict__ mg,
    const float* __restrict__ ws_boxes, const int* __restrict__ ws_keep,
    unsigned short* __restrict__ roi)
{
  const int box = blockIdx.x / 30;
  const int r   = blockIdx.x % 30;
  if (!ws_keep[box]) return;
  const int t = threadIdx.x;
  unsigned short* dst = roi + (((size_t)box * 30 + r) * 32) * 256;
  const int gr = r - 1;

  if (gr < 0 || gr > 27) {
    uint4 z = {0u, 0u, 0u, 0u};
    for (int e = t; e < 1024; e += 256) ((uint4*)dst)[e] = z;
    return;
  }

  __shared__ int   xa_s[MS], xb_s[MS];
  __shared__ float fx_s[MS];
  __shared__ float by_s[4];
  if (t < 4) by_s[t] = ws_boxes[box * 4 + t];
  __syncthreads();
  const float b0 = by_s[0] * 0.25f, b1_ = by_s[1] * 0.25f;
  const float b2_ = by_s[2] * 0.25f, b3_ = by_s[3] * 0.25f;
  if (t < MS) {
    float bw = (b2_ - b0) * (1.f / MS);
    float x = b0 + ((float)t + 0.5f) * bw;
    x = fminf(fmaxf(x, 0.f), 127.f);
    int x0 = (int)floorf(x);
    xa_s[t] = x0; xb_s[t] = min(x0 + 1, 127); fx_s[t] = x - (float)x0;
  }
  float bh = (b3_ - b1_) * (1.f / MS);
  float yy = b1_ + ((float)gr + 0.5f) * bh;
  yy = fminf(fmaxf(yy, 0.f), 127.f);
  int ya = (int)floorf(yy);
  int yb = min(ya + 1, 127);
  float fy = yy - (float)ya;
  __syncthreads();

  const int b = box >> 6;
  const unsigned short* mgb = mg + ((size_t)b * 128 * 128) * 256;

  // 1024 units of 8 ci: cell = e>>5, U = e&31 (c = U>>2, qi = U&3)
  for (int e = t; e < 1024; e += 256) {
    int cell = e >> 5, U = e & 31;
    int c = U >> 2, qi = U & 3;
    int slot = cell * 256 + c * 32 + ((qi ^ ((cell >> 1) & 3)) * 8);
    int gc = cell - 1;
    if (gc < 0 || gc > 27) {
      uint4 z = {0u, 0u, 0u, 0u};
      *(uint4*)(dst + slot) = z;
      continue;
    }
    int xa = xa_s[gc], xb = xb_s[gc];
    float fx = fx_s[gc];
    float w00 = (1.f - fy) * (1.f - fx), w01 = (1.f - fy) * fx;
    float w10 = fy * (1.f - fx),         w11 = fy * fx;
    uint4 A = *(const uint4*)(mgb + ((size_t)(ya * 128 + xa)) * 256 + U * 8);
    uint4 B = *(const uint4*)(mgb + ((size_t)(ya * 128 + xb)) * 256 + U * 8);
    uint4 C = *(const uint4*)(mgb + ((size_t)(yb * 128 + xa)) * 256 + U * 8);
    uint4 D = *(const uint4*)(mgb + ((size_t)(yb * 128 + xb)) * 256 + U * 8);
    const unsigned* pa = (const unsigned*)&A;
    const unsigned* pb = (const unsigned*)&B;
    const unsigned* pc = (const unsigned*)&C;
    const unsigned* pd = (const unsigned*)&D;
    unsigned o[4];
    #pragma unroll
    for (int k2 = 0; k2 < 4; ++k2) {
      float lo = bf2f(pa[k2] & 0xffffu) * w00 + bf2f(pb[k2] & 0xffffu) * w01 +
                 bf2f(pc[k2] & 0xffffu) * w10 + bf2f(pd[k2] & 0xffffu) * w11;
      float hi = bf2f(pa[k2] >> 16) * w00 + bf2f(pb[k2] >> 16) * w01 +
                 bf2f(pc[k2] >> 16) * w10 + bf2f(pd[k2] >> 16) * w11;
      o[k2] = (unsigned)f2bf(lo) | ((unsigned)f2bf(hi) << 16);
    }
    uint4 pk; pk.x = o[0]; pk.y = o[1]; pk.z = o[2]; pk.w = o[3];
    *(uint4*)(dst + slot) = pk;
  }
}

// ------- Kernel G: conv1 3x3 as 9 shifted MFMA GEMMs + SiLU + conv2 --------
// grid: box(128) x quarter(4) x cohalf(2) = 1024 blocks, 256 threads (4 waves)
// wave: nthalf = wv&1 (pixels 0-111 / 112-195), coq = wv>>1 (32 co each)
__global__ __launch_bounds__(256) void k_conv(
    const unsigned short* __restrict__ roi,
    const unsigned short* __restrict__ wt,
    const float* __restrict__ b1, const float* __restrict__ w2,
    const int* __restrict__ ws_keep,
    float* __restrict__ ws_logit2)   // [128][2][784]
{
  const int bid = blockIdx.x;
  const int box = bid >> 3;
  if (!ws_keep[box]) return;
  const int q  = (bid >> 1) & 3;
  const int ch = bid & 1;
  const int t = threadIdx.x;
  const int lane = t & 63, wv = t >> 6;
  const int laneN = lane & 15, kg = lane >> 4;
  const int nthalf = wv & 1, coq = wv >> 1;
  const int cobase = ch * 64 + coq * 32;

  __shared__ unsigned short bt[2][9 * 32 * 32];   // [buf][r][cell][ci32] swizzled
  __shared__ float lsum[2][7][16][2];

  const unsigned short* rbox = roi + ((size_t)box * 30) * 32 * 256;
  const int r0g = q * 7;

  int pxv[7], pyv[7];
  #pragma unroll
  for (int i = 0; i < 7; ++i) {
    int p = nthalf * 112 + i * 16 + laneN;
    if (p > 195) p = 195;
    pyv[i] = p / 28; pxv[i] = p - pyv[i] * 28;
  }
  int badd[7][3];
  #pragma unroll
  for (int i = 0; i < 7; ++i)
    #pragma unroll
    for (int dx = 0; dx < 3; ++dx) {
      int cell = pxv[i] + dx;
      badd[i][dx] = (pyv[i] * 32 + cell) * 32 + ((kg ^ ((cell >> 1) & 3)) * 8);
    }

  f32x4 acc[2][7];
  #pragma unroll
  for (int mt = 0; mt < 2; ++mt)
    #pragma unroll
    for (int i = 0; i < 7; ++i) acc[mt][i] = (f32x4){0.f, 0.f, 0.f, 0.f};

  const bf16x8* wtl = (const bf16x8*)wt;
  int aoff[2];
  #pragma unroll
  for (int mt = 0; mt < 2; ++mt) aoff[mt] = (cobase + mt * 16 + laneN) * 32 + kg;

  const unsigned short* srcb = rbox + r0g * 32 * 256;

  auto copyB = [&](int c, int buf) {
    const unsigned short* src = srcb + c * 32;
    unsigned short* d = bt[buf];
    #pragma unroll
    for (int ii = 0; ii < 5; ++ii) {
      int e = t + ii * 256;
      if (e < 1152) {
        int rc = e >> 2, qs = e & 3;
        uint4 v = *(const uint4*)(src + (size_t)rc * 256 + qs * 8);
        *(uint4*)(d + e * 8) = v;
      }
    }
  };

  copyB(0, 0);
  __syncthreads();
  for (int c = 0; c < 8; ++c) {
    if (c < 7) copyB(c + 1, (c + 1) & 1);
    const unsigned short* rb = bt[c & 1];
    #pragma unroll
    for (int tap = 0; tap < 9; ++tap) {
      const int dy = tap / 3, dx = tap % 3;
      bf16x8 av0 = wtl[aoff[0] + tap * 4096 + c * 4];
      bf16x8 av1 = wtl[aoff[1] + tap * 4096 + c * 4];
      #pragma unroll
      for (int i = 0; i < 7; ++i) {
        bf16x8 bv = *(const bf16x8*)(rb + badd[i][dx] + dy * 1024);
        acc[0][i] = __builtin_amdgcn_mfma_f32_16x16x32_bf16(av0, bv, acc[0][i], 0, 0, 0);
        acc[1][i] = __builtin_amdgcn_mfma_f32_16x16x32_bf16(av1, bv, acc[1][i], 0, 0, 0);
      }
    }
    __syncthreads();
  }

  float b1v[2][4], w2v[2][4];
  #pragma unroll
  for (int mt = 0; mt < 2; ++mt)
    #pragma unroll
    for (int r = 0; r < 4; ++r) {
      int co = cobase + mt * 16 + kg * 4 + r;
      b1v[mt][r] = b1[co];
      w2v[mt][r] = w2[co];
    }
  #pragma unroll
  for (int i = 0; i < 7; ++i) {
    float part = 0.f;
    #pragma unroll
    for (int mt = 0; mt < 2; ++mt)
      #pragma unroll
      for (int r = 0; r < 4; ++r) {
        float h = acc[mt][i][r] + b1v[mt][r];
        part = fmaf(w2v[mt][r], h * sigmoidf_(h), part);
      }
    part += __shfl_xor(part, 16);
    part += __shfl_xor(part, 32);
    if (lane < 16) lsum[nthalf][i][laneN][coq] = part;
  }
  __syncthreads();
  if (t < 196) {
    int nh = t / 112, rem = t - nh * 112;
    int i = rem >> 4, n = rem & 15;
    ws_logit2[((size_t)box * 2 + ch) * 784 + q * 196 + t] =
        lsum[nh][i][n][0] + lsum[nh][i][n][1];
  }
}

// ---------------- Kernel D: sigmoid + paste + binarize (f32 out) ------------
// grid: box(128) x row-quarter(4) = 512 blocks
__global__ __launch_bounds__(256) void k_paste(
    const float* __restrict__ ws_logit2, const int* __restrict__ ws_keep,
    const int* __restrict__ ws_boxint, const float* __restrict__ b2,
    float* __restrict__ out)
{
  const int box = blockIdx.x >> 2;
  const int yq  = blockIdx.x & 3;
  const int t = threadIdx.x;
  float* mb = out + OFF_MASKS + (size_t)box * 262144 + (size_t)yq * 128 * 512;

  if (!ws_keep[box]) {
    uint4 z = {0u, 0u, 0u, 0u};
    uint4* p = (uint4*)mb;
    for (int e = t; e < 16384; e += 256) p[e] = z;
    return;
  }

  __shared__ float soft[784];
  __shared__ int ixs[512], iys[128];
  __shared__ int bi[4];
  if (t < 4) bi[t] = ws_boxint[box * 4 + t];
  __syncthreads();
  const int x0 = bi[0], y0 = bi[1], x1 = bi[2], y1 = bi[3];
  const int w = x1 - x0 + 1, h = y1 - y0 + 1;
  const float b2v = b2[0];
  const float* l0 = ws_logit2 + (size_t)box * 2 * 784;

  for (int e = t; e < 784; e += 256)
    soft[e] = sigmoidf_(l0[e] + l0[784 + e] + b2v);
  for (int e = t; e < 512; e += 256) {
    int vx = (e - x0) * MS;
    int ix = (vx >= 0) ? (vx / w) : 0;
    ixs[e] = min(max(ix, 0), MS - 1);
  }
  if (t < 128) {
    int Y = yq * 128 + t;
    int vy = (Y - y0) * MS;
    int iy = (vy >= 0) ? (vy / h) : 0;
    iys[t] = min(max(iy, 0), MS - 1);
  }
  __syncthreads();

  const unsigned FONE = 0x3F800000u;
  for (int it = 0; it < 32; ++it) {
    int Yl = it * 4 + (t >> 6);
    int Y = yq * 128 + Yl;
    int Xb = (t & 63) * 8;
    bool rowin = (Y >= y0) && (Y <= y1);
    int iy = iys[Yl];
    unsigned v[8];
    #pragma unroll
    for (int u = 0; u < 8; ++u) {
      int X = Xb + u;
      bool in = rowin && (X >= x0) && (X <= x1);
      float g = soft[iy * MS + ixs[X]];
      v[u] = (in && g > 0.5f) ? FONE : 0u;
    }
    uint4 pk0, pk1;
    pk0.x = v[0]; pk0.y = v[1]; pk0.z = v[2]; pk0.w = v[3];
    pk1.x = v[4]; pk1.y = v[5]; pk1.z = v[6]; pk1.w = v[7];
    *(uint4*)(mb + (size_t)Yl * 512 + Xb) = pk0;
    *(uint4*)(mb + (size_t)Yl * 512 + Xb + 4) = pk1;
  }
}

extern "C" void kernel_launch(void* const* d_in, const int* in_sizes, int n_in,
                              void* d_out, int out_size, void* d_ws, size_t ws_size,
                              hipStream_t stream) {
  const float* p0 = (const float*)d_in[0];
  const float* p1 = (const float*)d_in[1];
  const float* p2 = (const float*)d_in[2];
  const float* p3 = (const float*)d_in[3];
  const float* f0 = (const float*)d_in[4];
  const float* f1 = (const float*)d_in[5];
  const float* f2 = (const float*)d_in[6];
  const float* f3 = (const float*)d_in[7];
  const float* w1 = (const float*)d_in[8];
  const float* b1 = (const float*)d_in[9];
  const float* w2 = (const float*)d_in[10];
  const float* b2 = (const float*)d_in[11];
  float* out = (float*)d_out;

  float* wsf = (float*)d_ws;
  float*          ws_boxes  = wsf;                               // 512 f32
  int*            ws_keep   = (int*)(wsf + 512);                 // 128
  int*            ws_boxint = (int*)(wsf + 640);                 // 512
  float*          ws_logit2 = wsf + 1152;                        // 128*2*784
  unsigned short* ws_wt     = (unsigned short*)(wsf + 201856);   // 9*128*256 bf16
  unsigned short* ws_merged = (unsigned short*)(wsf + 349312);   // 2*128*128*256 bf16
  unsigned short* ws_roi    = (unsigned short*)(wsf + 4543616);  // 128*30*32*256 bf16
  // total ws use: 20,272,256 f32 = 81.1 MB

  k_decode<<<2, 384, 0, stream>>>(p0, p1, p2, p3, out, ws_boxes, ws_keep, ws_boxint);
  k_transw<<<128, 256, 0, stream>>>(w1, ws_wt);
  k_transpose<<<256, 256, 0, stream>>>(f0, f1, f2, f3, ws_merged);
  k_roistage<<<3840, 256, 0, stream>>>(ws_merged, ws_boxes, ws_keep, ws_roi);
  k_conv<<<1024, 256, 0, stream>>>(ws_roi, ws_wt, b1, w2, ws_keep, ws_logit2);
  k_paste<<<512, 256, 0, stream>>>(ws_logit2, ws_keep, ws_boxint, b2, out);
}